// Round 8
// baseline (286.849 us; speedup 1.0000x reference)
//
#include <hip/hip_runtime.h>
#include <math.h>

#define BATCH   256
#define NCAPS   10
#define RROWS   1152
#define CI      8
#define CO      16
#define HCO     8            // half of CO; thread pair (t, t^1) splits CO
#define THREADS 768
#define ITEMS   3            // (RROWS*2 halves)/THREADS = 2304/768
#define GBAT    2            // batches per block: W n-slice amortized over GBAT
#define NWAVES  (THREADS/64)
#define NITER   3
#define BPG     (BATCH/GBAT) // 128 blocks per capsule n

__device__ __forceinline__ float wave_allred_sum(float v) {
  #pragma unroll
  for (int off = 32; off >= 1; off >>= 1) v += __shfl_xor(v, off, 64);
  return v;
}
__device__ __forceinline__ float wave_allred_max(float v) {
  #pragma unroll
  for (int off = 32; off >= 1; off >>= 1) v = fmaxf(v, __shfl_xor(v, off, 64));
  return v;
}

// Each lane holds v[0..7] = components 8*(lane&1)+p. Returns (in every lane)
// the 64-lane sum of component comp16(lane&15); 9 shuffles total.
__device__ __forceinline__ float xpose_reduce8(const float (&v)[HCO], int lane) {
  float a[4], b[2], c;
  const bool k2 = (lane & 2) != 0;
  #pragma unroll
  for (int p = 0; p < 4; ++p) {
    float send = k2 ? v[p] : v[p + 4];
    float keep = k2 ? v[p + 4] : v[p];
    a[p] = keep + __shfl_xor(send, 2, 64);
  }
  const bool k4 = (lane & 4) != 0;
  #pragma unroll
  for (int p = 0; p < 2; ++p) {
    float send = k4 ? a[p] : a[p + 2];
    float keep = k4 ? a[p + 2] : a[p];
    b[p] = keep + __shfl_xor(send, 4, 64);
  }
  const bool k8 = (lane & 8) != 0;
  {
    float send = k8 ? b[0] : b[1];
    float keep = k8 ? b[1] : b[0];
    c = keep + __shfl_xor(send, 8, 64);
  }
  c += __shfl_xor(c, 16, 64);
  c += __shfl_xor(c, 32, 64);
  return c;
}
// component index held by lane l after xpose_reduce8 (bit-reversal, bijective)
__device__ __forceinline__ int comp16(int l) {
  return 8 * (l & 1) + 4 * ((l >> 1) & 1) + 2 * ((l >> 2) & 1) + ((l >> 3) & 1);
}

// (768, 3): min 3 waves/SIMD -> VGPR cap ~170 (1 block/CU). Without this the
// compiler targets 2 blocks/CU (84 VGPRs) and spills the prior array to
// scratch: round-7 counters showed 361 MB WRITE_SIZE of pure spill traffic.
__global__ __launch_bounds__(THREADS, 3) void caps_route(
    const float* __restrict__ x,     // [B, R, CI]
    const float* __restrict__ W,     // [N, R, CI, CO]
    float* __restrict__ out) {       // [N, B, CO]
  const int bid  = blockIdx.x;
  const int n    = bid / BPG;        // n-major: concurrent blocks share one 590KB W slice in L2
  const int b0   = (bid % BPG) * GBAT;
  const int t    = threadIdx.x;
  const int wave = t >> 6;
  const int lane = t & 63;
  const int h    = t & 1;            // my co-half: [h*8, h*8+8)
  const int rb   = t >> 1;           // base row; rows are rb + 384*k

  __shared__ __align__(16) float red[GBAT][NWAVES][CO];
  __shared__ float wredA[GBAT][NWAVES];
  __shared__ float wredB[GBAT][NWAVES];
  __shared__ __align__(16) float vsh[GBAT][CO];

  const float* __restrict__ Wn = W + (size_t)n * (RROWS * CI * CO);

  float prior[GBAT][ITEMS][HCO];     // 48 VGPRs; must stay in registers
  float logit_[GBAT][ITEMS];

  // ---- Phase 1: priors. Each W element loaded once, used for GBAT batches.
  #pragma unroll
  for (int k = 0; k < ITEMS; ++k) {
    const int r = rb + k * (THREADS / 2);
    float xv[GBAT][CI];
    #pragma unroll
    for (int g = 0; g < GBAT; ++g) {
      const float* xb = x + ((size_t)(b0 + g) * RROWS + r) * CI;
      const float4 x0 = *reinterpret_cast<const float4*>(xb);
      const float4 x1 = *reinterpret_cast<const float4*>(xb + 4);
      xv[g][0] = x0.x; xv[g][1] = x0.y; xv[g][2] = x0.z; xv[g][3] = x0.w;
      xv[g][4] = x1.x; xv[g][5] = x1.y; xv[g][6] = x1.z; xv[g][7] = x1.w;
      #pragma unroll
      for (int p = 0; p < HCO; ++p) prior[g][k][p] = 0.f;
      logit_[g][k] = 0.f;
    }
    // W[r][c][h*8 + 0..7], c = 0..7  (32B-aligned float4 pairs)
    const float4* wr = reinterpret_cast<const float4*>(Wn + (size_t)r * (CI * CO) + h * HCO);
    #pragma unroll
    for (int c = 0; c < CI; ++c) {
      const float4 wa = wr[c * 4 + 0];
      const float4 wb = wr[c * 4 + 1];
      #pragma unroll
      for (int g = 0; g < GBAT; ++g) {
        const float xc = xv[g][c];
        prior[g][k][0] = fmaf(xc, wa.x, prior[g][k][0]);
        prior[g][k][1] = fmaf(xc, wa.y, prior[g][k][1]);
        prior[g][k][2] = fmaf(xc, wa.z, prior[g][k][2]);
        prior[g][k][3] = fmaf(xc, wa.w, prior[g][k][3]);
        prior[g][k][4] = fmaf(xc, wb.x, prior[g][k][4]);
        prior[g][k][5] = fmaf(xc, wb.y, prior[g][k][5]);
        prior[g][k][6] = fmaf(xc, wb.z, prior[g][k][6]);
        prior[g][k][7] = fmaf(xc, wb.w, prior[g][k][7]);
      }
    }
  }

  // ---- Phase 2: 3 routing iterations, priors stay in registers ------------
  #pragma unroll
  for (int it = 0; it < NITER; ++it) {
    float wj[GBAT][ITEMS];
    if (it == 0) {
      #pragma unroll
      for (int g = 0; g < GBAT; ++g)
        #pragma unroll
        for (int k = 0; k < ITEMS; ++k) wj[g][k] = 1.0f / (float)RROWS;
    } else {
      // softmax over R per (n, b0+g). Each row's logit is held (bit-identically)
      // by BOTH parity threads of a pair -> max unaffected; sum scaled by 0.5.
      #pragma unroll
      for (int g = 0; g < GBAT; ++g) {
        float lm = fmaxf(fmaxf(logit_[g][0], logit_[g][1]), logit_[g][2]);
        lm = wave_allred_max(lm);
        if (lane == 0) wredA[g][wave] = lm;
      }
      __syncthreads();                                  // (A)
      float eg[GBAT][ITEMS];
      #pragma unroll
      for (int g = 0; g < GBAT; ++g) {
        float m = wredA[g][0];
        #pragma unroll
        for (int w = 1; w < NWAVES; ++w) m = fmaxf(m, wredA[g][w]);
        #pragma unroll
        for (int k = 0; k < ITEMS; ++k) eg[g][k] = __expf(logit_[g][k] - m);
        float ls = wave_allred_sum(0.5f * (eg[g][0] + eg[g][1] + eg[g][2]));
        if (lane == 0) wredB[g][wave] = ls;
      }
      __syncthreads();                                  // (B)
      #pragma unroll
      for (int g = 0; g < GBAT; ++g) {
        float Z = wredB[g][0];
        #pragma unroll
        for (int w = 1; w < NWAVES; ++w) Z += wredB[g][w];
        const float invZ = 1.0f / Z;
        #pragma unroll
        for (int k = 0; k < ITEMS; ++k) wj[g][k] = eg[g][k] * invZ;
      }
    }

    // s[o] = sum_r probs[r]*prior[r][o]; each (r,o) is owned by exactly one thread
    #pragma unroll
    for (int g = 0; g < GBAT; ++g) {
      float ps[HCO];
      #pragma unroll
      for (int p = 0; p < HCO; ++p)
        ps[p] = fmaf(wj[g][0], prior[g][0][p],
                fmaf(wj[g][1], prior[g][1][p], wj[g][2] * prior[g][2][p]));
      const float psum = xpose_reduce8(ps, lane);
      if (lane < CO) red[g][wave][comp16(lane)] = psum;
    }
    __syncthreads();                                    // (C)
    if (t < GBAT * CO) {                                // threads 0..31, wave 0
      const int g = t >> 4;
      const int o = t & (CO - 1);
      float s = red[g][0][o];
      #pragma unroll
      for (int w = 1; w < NWAVES; ++w) s += red[g][w][o];
      float s2 = s * s;
      #pragma unroll
      for (int off = 8; off >= 1; off >>= 1) s2 += __shfl_xor(s2, off, 16);
      const float scale = sqrtf(s2) / (1.0f + s2);      // squash: s*sqrt(n)/(1+n)
      const float v = s * scale;
      vsh[g][o] = v;
      if (it == NITER - 1) out[((size_t)n * BATCH + (b0 + g)) * CO + o] = v;
    }
    __syncthreads();                                    // (D)

    if (it < NITER - 1) {
      #pragma unroll
      for (int g = 0; g < GBAT; ++g) {
        // my co-half of v, then pair-combine for the full dot product
        const float4 va = *reinterpret_cast<const float4*>(&vsh[g][h * HCO]);
        const float4 vb = *reinterpret_cast<const float4*>(&vsh[g][h * HCO + 4]);
        const float vv[HCO] = {va.x, va.y, va.z, va.w, vb.x, vb.y, vb.z, vb.w};
        #pragma unroll
        for (int k = 0; k < ITEMS; ++k) {
          float d = 0.f;
          #pragma unroll
          for (int p = 0; p < HCO; ++p) d = fmaf(prior[g][k][p], vv[p], d);
          logit_[g][k] += d + __shfl_xor(d, 1, 64);     // add partner's half
        }
      }
    }
  }
}

extern "C" void kernel_launch(void* const* d_in, const int* in_sizes, int n_in,
                              void* d_out, int out_size, void* d_ws, size_t ws_size,
                              hipStream_t stream) {
  const float* x = (const float*)d_in[0];
  const float* W = (const float*)d_in[1];
  float* out = (float*)d_out;
  dim3 grid(NCAPS * BPG);
  dim3 block(THREADS);
  hipLaunchKernelGGL(caps_route, grid, block, 0, stream, x, W, out);
}

// Round 9
// 271.110 us; speedup vs baseline: 1.0581x; 1.0581x over previous
//
#include <hip/hip_runtime.h>
#include <math.h>

#define BATCH   256
#define NCAPS   10
#define RROWS   1152
#define CI      8
#define CO      16
#define HCO     8            // half of CO; thread pair (t, t^1) splits CO
#define THREADS 768
#define ITEMS   3            // (RROWS*2 halves)/THREADS = 2304/768
#define GBAT    2            // batches per block: W n-slice amortized over GBAT
#define NWAVES  (THREADS/64)
#define NITER   3
#define BPG     (BATCH/GBAT) // 128 blocks per capsule n

__device__ __forceinline__ float wave_allred_sum(float v) {
  #pragma unroll
  for (int off = 32; off >= 1; off >>= 1) v += __shfl_xor(v, off, 64);
  return v;
}
__device__ __forceinline__ float wave_allred_max(float v) {
  #pragma unroll
  for (int off = 32; off >= 1; off >>= 1) v = fmaxf(v, __shfl_xor(v, off, 64));
  return v;
}

// Each lane holds v[0..7] = components 8*(lane&1)+p. Returns (in every lane)
// the 64-lane sum of component comp16(lane&15); 9 shuffles total.
__device__ __forceinline__ float xpose_reduce8(const float (&v)[HCO], int lane) {
  float a[4], b[2], c;
  const bool k2 = (lane & 2) != 0;
  #pragma unroll
  for (int p = 0; p < 4; ++p) {
    float send = k2 ? v[p] : v[p + 4];
    float keep = k2 ? v[p + 4] : v[p];
    a[p] = keep + __shfl_xor(send, 2, 64);
  }
  const bool k4 = (lane & 4) != 0;
  #pragma unroll
  for (int p = 0; p < 2; ++p) {
    float send = k4 ? a[p] : a[p + 2];
    float keep = k4 ? a[p + 2] : a[p];
    b[p] = keep + __shfl_xor(send, 4, 64);
  }
  const bool k8 = (lane & 8) != 0;
  {
    float send = k8 ? b[0] : b[1];
    float keep = k8 ? b[1] : b[0];
    c = keep + __shfl_xor(send, 8, 64);
  }
  c += __shfl_xor(c, 16, 64);
  c += __shfl_xor(c, 32, 64);
  return c;
}
// component index held by lane l after xpose_reduce8 (bit-reversal, bijective)
__device__ __forceinline__ int comp16(int l) {
  return 8 * (l & 1) + 4 * ((l >> 1) & 1) + 2 * ((l >> 2) & 1) + ((l >> 3) & 1);
}

// amdgpu_waves_per_eu(2,3): the MAX=3 is the load-bearing part. The GCN
// scheduler targets the maximum achievable occupancy (6 waves/EU for 12-wave
// blocks -> 84-VGPR cap) and SPILLS to reach it: rounds 7/8 measured 361 MB
// of scratch writes at VGPR_Count=84. launch_bounds' 2nd arg only sets the
// MIN (can't raise the cap - round 8 proved it's a no-op here). Capping the
// occupancy target at 3 waves/EU (1 block/CU) gives the allocator ~170 VGPRs,
// so the 48-reg prior array stays in registers.
__global__ __launch_bounds__(THREADS)
__attribute__((amdgpu_waves_per_eu(2, 3)))
void caps_route(
    const float* __restrict__ x,     // [B, R, CI]
    const float* __restrict__ W,     // [N, R, CI, CO]
    float* __restrict__ out) {       // [N, B, CO]
  const int bid  = blockIdx.x;
  const int n    = bid / BPG;        // n-major: concurrent blocks share one 590KB W slice in L2
  const int b0   = (bid % BPG) * GBAT;
  const int t    = threadIdx.x;
  const int wave = t >> 6;
  const int lane = t & 63;
  const int h    = t & 1;            // my co-half: [h*8, h*8+8)
  const int rb   = t >> 1;           // base row; rows are rb + 384*k

  __shared__ __align__(16) float red[GBAT][NWAVES][CO];
  __shared__ float wredA[GBAT][NWAVES];
  __shared__ float wredB[GBAT][NWAVES];
  __shared__ __align__(16) float vsh[GBAT][CO];

  const float* __restrict__ Wn = W + (size_t)n * (RROWS * CI * CO);

  float prior[GBAT][ITEMS][HCO];     // 48 VGPRs; must stay in registers
  float logit_[GBAT][ITEMS];

  // ---- Phase 1: priors. Each W element loaded once, used for GBAT batches.
  #pragma unroll
  for (int k = 0; k < ITEMS; ++k) {
    const int r = rb + k * (THREADS / 2);
    float xv[GBAT][CI];
    #pragma unroll
    for (int g = 0; g < GBAT; ++g) {
      const float* xb = x + ((size_t)(b0 + g) * RROWS + r) * CI;
      const float4 x0 = *reinterpret_cast<const float4*>(xb);
      const float4 x1 = *reinterpret_cast<const float4*>(xb + 4);
      xv[g][0] = x0.x; xv[g][1] = x0.y; xv[g][2] = x0.z; xv[g][3] = x0.w;
      xv[g][4] = x1.x; xv[g][5] = x1.y; xv[g][6] = x1.z; xv[g][7] = x1.w;
      #pragma unroll
      for (int p = 0; p < HCO; ++p) prior[g][k][p] = 0.f;
      logit_[g][k] = 0.f;
    }
    // W[r][c][h*8 + 0..7], c = 0..7  (32B-aligned float4 pairs)
    const float4* wr = reinterpret_cast<const float4*>(Wn + (size_t)r * (CI * CO) + h * HCO);
    #pragma unroll
    for (int c = 0; c < CI; ++c) {
      const float4 wa = wr[c * 4 + 0];
      const float4 wb = wr[c * 4 + 1];
      #pragma unroll
      for (int g = 0; g < GBAT; ++g) {
        const float xc = xv[g][c];
        prior[g][k][0] = fmaf(xc, wa.x, prior[g][k][0]);
        prior[g][k][1] = fmaf(xc, wa.y, prior[g][k][1]);
        prior[g][k][2] = fmaf(xc, wa.z, prior[g][k][2]);
        prior[g][k][3] = fmaf(xc, wa.w, prior[g][k][3]);
        prior[g][k][4] = fmaf(xc, wb.x, prior[g][k][4]);
        prior[g][k][5] = fmaf(xc, wb.y, prior[g][k][5]);
        prior[g][k][6] = fmaf(xc, wb.z, prior[g][k][6]);
        prior[g][k][7] = fmaf(xc, wb.w, prior[g][k][7]);
      }
    }
  }

  // ---- Phase 2: 3 routing iterations, priors stay in registers ------------
  #pragma unroll
  for (int it = 0; it < NITER; ++it) {
    float wj[GBAT][ITEMS];
    if (it == 0) {
      #pragma unroll
      for (int g = 0; g < GBAT; ++g)
        #pragma unroll
        for (int k = 0; k < ITEMS; ++k) wj[g][k] = 1.0f / (float)RROWS;
    } else {
      // softmax over R per (n, b0+g). Each row's logit is held (bit-identically)
      // by BOTH parity threads of a pair -> max unaffected; sum scaled by 0.5.
      #pragma unroll
      for (int g = 0; g < GBAT; ++g) {
        float lm = fmaxf(fmaxf(logit_[g][0], logit_[g][1]), logit_[g][2]);
        lm = wave_allred_max(lm);
        if (lane == 0) wredA[g][wave] = lm;
      }
      __syncthreads();                                  // (A)
      float eg[GBAT][ITEMS];
      #pragma unroll
      for (int g = 0; g < GBAT; ++g) {
        float m = wredA[g][0];
        #pragma unroll
        for (int w = 1; w < NWAVES; ++w) m = fmaxf(m, wredA[g][w]);
        #pragma unroll
        for (int k = 0; k < ITEMS; ++k) eg[g][k] = __expf(logit_[g][k] - m);
        float ls = wave_allred_sum(0.5f * (eg[g][0] + eg[g][1] + eg[g][2]));
        if (lane == 0) wredB[g][wave] = ls;
      }
      __syncthreads();                                  // (B)
      #pragma unroll
      for (int g = 0; g < GBAT; ++g) {
        float Z = wredB[g][0];
        #pragma unroll
        for (int w = 1; w < NWAVES; ++w) Z += wredB[g][w];
        const float invZ = 1.0f / Z;
        #pragma unroll
        for (int k = 0; k < ITEMS; ++k) wj[g][k] = eg[g][k] * invZ;
      }
    }

    // s[o] = sum_r probs[r]*prior[r][o]; each (r,o) is owned by exactly one thread
    #pragma unroll
    for (int g = 0; g < GBAT; ++g) {
      float ps[HCO];
      #pragma unroll
      for (int p = 0; p < HCO; ++p)
        ps[p] = fmaf(wj[g][0], prior[g][0][p],
                fmaf(wj[g][1], prior[g][1][p], wj[g][2] * prior[g][2][p]));
      const float psum = xpose_reduce8(ps, lane);
      if (lane < CO) red[g][wave][comp16(lane)] = psum;
    }
    __syncthreads();                                    // (C)
    if (t < GBAT * CO) {                                // threads 0..31, wave 0
      const int g = t >> 4;
      const int o = t & (CO - 1);
      float s = red[g][0][o];
      #pragma unroll
      for (int w = 1; w < NWAVES; ++w) s += red[g][w][o];
      float s2 = s * s;
      #pragma unroll
      for (int off = 8; off >= 1; off >>= 1) s2 += __shfl_xor(s2, off, 16);
      const float scale = sqrtf(s2) / (1.0f + s2);      // squash: s*sqrt(n)/(1+n)
      const float v = s * scale;
      vsh[g][o] = v;
      if (it == NITER - 1) out[((size_t)n * BATCH + (b0 + g)) * CO + o] = v;
    }
    __syncthreads();                                    // (D)

    if (it < NITER - 1) {
      #pragma unroll
      for (int g = 0; g < GBAT; ++g) {
        // my co-half of v, then pair-combine for the full dot product
        const float4 va = *reinterpret_cast<const float4*>(&vsh[g][h * HCO]);
        const float4 vb = *reinterpret_cast<const float4*>(&vsh[g][h * HCO + 4]);
        const float vv[HCO] = {va.x, va.y, va.z, va.w, vb.x, vb.y, vb.z, vb.w};
        #pragma unroll
        for (int k = 0; k < ITEMS; ++k) {
          float d = 0.f;
          #pragma unroll
          for (int p = 0; p < HCO; ++p) d = fmaf(prior[g][k][p], vv[p], d);
          logit_[g][k] += d + __shfl_xor(d, 1, 64);     // add partner's half
        }
      }
    }
  }
}

extern "C" void kernel_launch(void* const* d_in, const int* in_sizes, int n_in,
                              void* d_out, int out_size, void* d_ws, size_t ws_size,
                              hipStream_t stream) {
  const float* x = (const float*)d_in[0];
  const float* W = (const float*)d_in[1];
  float* out = (float*)d_out;
  dim3 grid(NCAPS * BPG);
  dim3 block(THREADS);
  hipLaunchKernelGGL(caps_route, grid, block, 0, stream, x, W, out);
}

// Round 12
// 158.612 us; speedup vs baseline: 1.8085x; 1.7093x over previous
//
#include <hip/hip_runtime.h>
#include <math.h>

#define BATCH   256
#define NCAPS   10
#define RROWS   1152
#define CI      8
#define CO      16
#define HCO     8            // half of CO; thread pair (t, t^1) splits CO
#define THREADS 768
#define ITEMS   3            // rows per thread: (t>>1) + 384*k, 1152/(768/2) = 3
#define NWAVES  (THREADS/64)
#define NITER   3

// GBAT=1 (one batch per block). Rounds 3/7/8/9 proved the allocator enforces
// a ~4 waves/EU occupancy floor and spills to reach it (VGPR caps 128/84; 361MB
// scratch writes at GBAT=2's 48-reg prior array). Neither __launch_bounds__
// min nor amdgpu_waves_per_eu raised the cap. At GBAT=1 peak live regs ~55,
// which fits under ANY observed cap -> spill structurally impossible.

__device__ __forceinline__ float wave_allred_sum(float v) {
  #pragma unroll
  for (int off = 32; off >= 1; off >>= 1) v += __shfl_xor(v, off, 64);
  return v;
}
__device__ __forceinline__ float wave_allred_max(float v) {
  #pragma unroll
  for (int off = 32; off >= 1; off >>= 1) v = fmaxf(v, __shfl_xor(v, off, 64));
  return v;
}

// Each lane holds v[0..7] = components 8*(lane&1)+p. Returns (in every lane)
// the 64-lane sum of component comp16(lane&15); 9 shuffles total.
__device__ __forceinline__ float xpose_reduce8(const float (&v)[HCO], int lane) {
  float a[4], b[2], c;
  const bool k2 = (lane & 2) != 0;
  #pragma unroll
  for (int p = 0; p < 4; ++p) {
    float send = k2 ? v[p] : v[p + 4];
    float keep = k2 ? v[p + 4] : v[p];
    a[p] = keep + __shfl_xor(send, 2, 64);
  }
  const bool k4 = (lane & 4) != 0;
  #pragma unroll
  for (int p = 0; p < 2; ++p) {
    float send = k4 ? a[p] : a[p + 2];
    float keep = k4 ? a[p + 2] : a[p];
    b[p] = keep + __shfl_xor(send, 4, 64);
  }
  const bool k8 = (lane & 8) != 0;
  {
    float send = k8 ? b[0] : b[1];
    float keep = k8 ? b[1] : b[0];
    c = keep + __shfl_xor(send, 8, 64);
  }
  c += __shfl_xor(c, 16, 64);
  c += __shfl_xor(c, 32, 64);
  return c;
}
// component index held by lane l after xpose_reduce8 (bit-reversal, bijective)
__device__ __forceinline__ int comp16(int l) {
  return 8 * (l & 1) + 4 * ((l >> 1) & 1) + 2 * ((l >> 2) & 1) + ((l >> 3) & 1);
}

__global__ __launch_bounds__(THREADS) void caps_route(
    const float* __restrict__ x,     // [B, R, CI]
    const float* __restrict__ W,     // [N, R, CI, CO]
    float* __restrict__ out) {       // [N, B, CO]
  const int bid  = blockIdx.x;
  const int n    = bid >> 8;         // n-major: concurrent blocks share one 576KB W slice in L2
  const int b    = bid & (BATCH - 1);
  const int t    = threadIdx.x;
  const int wave = t >> 6;
  const int lane = t & 63;
  const int h    = t & 1;            // my co-half: [h*8, h*8+8)
  const int rb   = t >> 1;           // base row; rows are rb + 384*k

  __shared__ __align__(16) float red[NWAVES][CO];
  __shared__ float wredA[NWAVES];
  __shared__ float wredB[NWAVES];
  __shared__ __align__(16) float vsh[CO];

  const float* __restrict__ Wn = W + (size_t)n * (RROWS * CI * CO);
  const float* __restrict__ xb = x + (size_t)b * (RROWS * CI);

  float prior[ITEMS][HCO];           // 24 VGPRs — fits under any occupancy cap
  float logit_[ITEMS];

  // ---- Phase 1: priors for my 3 (row, co-half) items ----------------------
  #pragma unroll
  for (int k = 0; k < ITEMS; ++k) {
    const int r = rb + k * (THREADS / 2);
    const float4 x0 = *reinterpret_cast<const float4*>(xb + (size_t)r * CI);
    const float4 x1 = *reinterpret_cast<const float4*>(xb + (size_t)r * CI + 4);
    const float xv[CI] = {x0.x, x0.y, x0.z, x0.w, x1.x, x1.y, x1.z, x1.w};
    #pragma unroll
    for (int p = 0; p < HCO; ++p) prior[k][p] = 0.f;
    logit_[k] = 0.f;
    // W[r][c][h*8 + 0..7], c = 0..7; pair (t, t^1) covers the full 512B row
    const float4* wr = reinterpret_cast<const float4*>(Wn + (size_t)r * (CI * CO) + h * HCO);
    #pragma unroll
    for (int c = 0; c < CI; ++c) {
      const float4 wa = wr[c * 4 + 0];
      const float4 wb = wr[c * 4 + 1];
      const float xc = xv[c];
      prior[k][0] = fmaf(xc, wa.x, prior[k][0]);
      prior[k][1] = fmaf(xc, wa.y, prior[k][1]);
      prior[k][2] = fmaf(xc, wa.z, prior[k][2]);
      prior[k][3] = fmaf(xc, wa.w, prior[k][3]);
      prior[k][4] = fmaf(xc, wb.x, prior[k][4]);
      prior[k][5] = fmaf(xc, wb.y, prior[k][5]);
      prior[k][6] = fmaf(xc, wb.z, prior[k][6]);
      prior[k][7] = fmaf(xc, wb.w, prior[k][7]);
    }
  }

  // ---- Phase 2: 3 routing iterations, priors stay in registers ------------
  #pragma unroll
  for (int it = 0; it < NITER; ++it) {
    float wj[ITEMS];
    if (it == 0) {
      #pragma unroll
      for (int k = 0; k < ITEMS; ++k) wj[k] = 1.0f / (float)RROWS;
    } else {
      // softmax over R. Each row's logit held (bit-identically) by BOTH parity
      // threads of a pair -> max unaffected; sum scaled by 0.5 (exact).
      float lm = fmaxf(fmaxf(logit_[0], logit_[1]), logit_[2]);
      lm = wave_allred_max(lm);
      if (lane == 0) wredA[wave] = lm;
      __syncthreads();                                  // (A)
      float m = wredA[0];
      #pragma unroll
      for (int w = 1; w < NWAVES; ++w) m = fmaxf(m, wredA[w]);
      float eg[ITEMS];
      #pragma unroll
      for (int k = 0; k < ITEMS; ++k) eg[k] = __expf(logit_[k] - m);
      float ls = wave_allred_sum(0.5f * (eg[0] + eg[1] + eg[2]));
      if (lane == 0) wredB[wave] = ls;
      __syncthreads();                                  // (B)
      float Z = wredB[0];
      #pragma unroll
      for (int w = 1; w < NWAVES; ++w) Z += wredB[w];
      const float invZ = 1.0f / Z;
      #pragma unroll
      for (int k = 0; k < ITEMS; ++k) wj[k] = eg[k] * invZ;
    }

    // s[o] = sum_r probs[r]*prior[r][o]; each (r,o) owned by exactly one thread
    float ps[HCO];
    #pragma unroll
    for (int p = 0; p < HCO; ++p)
      ps[p] = fmaf(wj[0], prior[0][p], fmaf(wj[1], prior[1][p], wj[2] * prior[2][p]));
    const float psum = xpose_reduce8(ps, lane);
    if (lane < CO) red[wave][comp16(lane)] = psum;
    __syncthreads();                                    // (C)
    if (t < CO) {                                       // threads 0..15, wave 0
      float s = red[0][t];
      #pragma unroll
      for (int w = 1; w < NWAVES; ++w) s += red[w][t];
      float s2 = s * s;
      #pragma unroll
      for (int off = 8; off >= 1; off >>= 1) s2 += __shfl_xor(s2, off, 16);
      const float scale = sqrtf(s2) / (1.0f + s2);      // squash: s*sqrt(n)/(1+n)
      const float v = s * scale;
      vsh[t] = v;
      if (it == NITER - 1) out[((size_t)n * BATCH + b) * CO + t] = v;
    }
    __syncthreads();                                    // (D)

    if (it < NITER - 1) {
      // my co-half of v, then pair-combine for the full dot product
      const float4 va = *reinterpret_cast<const float4*>(&vsh[h * HCO]);
      const float4 vb = *reinterpret_cast<const float4*>(&vsh[h * HCO + 4]);
      const float vv[HCO] = {va.x, va.y, va.z, va.w, vb.x, vb.y, vb.z, vb.w};
      #pragma unroll
      for (int k = 0; k < ITEMS; ++k) {
        float d = 0.f;
        #pragma unroll
        for (int p = 0; p < HCO; ++p) d = fmaf(prior[k][p], vv[p], d);
        logit_[k] += d + __shfl_xor(d, 1, 64);          // add partner's half
      }
    }
  }
}

extern "C" void kernel_launch(void* const* d_in, const int* in_sizes, int n_in,
                              void* d_out, int out_size, void* d_ws, size_t ws_size,
                              hipStream_t stream) {
  const float* x = (const float*)d_in[0];
  const float* W = (const float*)d_in[1];
  float* out = (float*)d_out;
  dim3 grid(NCAPS * BATCH);
  dim3 block(THREADS);
  hipLaunchKernelGGL(caps_route, grid, block, 0, stream, x, W, out);
}